// Round 1
// baseline (674.531 us; speedup 1.0000x reference)
//
#include <hip/hip_runtime.h>

#define N_HALF 4096
#define M_TOT  8192
#define K_DIM  256

// ws layout (bytes)
#define WS_SQ      0        // 8192 floats
#define WS_COLPART 32768    // 32*256 floats
#define WS_BAND    65536    // 1 double
#define WS_ACC     65544    // 1 double
#define WS_BYTES   65552

// ---------------- row sum-of-squares: sq[r] = sum_k t[r,k]^2 ----------------
__global__ void k_rowsq(const float* __restrict__ src, const float* __restrict__ tgt,
                        float* __restrict__ sq) {
    int wave = threadIdx.x >> 6, lane = threadIdx.x & 63;
    int row  = (blockIdx.x << 2) + wave;
    const float* base = (row < N_HALF) ? (src + (size_t)row * K_DIM)
                                       : (tgt + (size_t)(row - N_HALF) * K_DIM);
    float4 v = *(const float4*)(base + (lane << 2));
    float s = v.x * v.x + v.y * v.y + v.z * v.z + v.w * v.w;
#pragma unroll
    for (int off = 32; off > 0; off >>= 1) s += __shfl_down(s, off, 64);
    if (lane == 0) sq[row] = s;
}

// ---------------- column partial sums (deterministic two-phase) -------------
__global__ void k_colpart(const float* __restrict__ src, const float* __restrict__ tgt,
                          float* __restrict__ colpart) {
    int c = threadIdx.x;          // column 0..255
    int b = blockIdx.x;           // 32 blocks, 256 rows each
    int row0 = b << 8;
    float s = 0.f;
    for (int r = 0; r < 256; ++r) {
        int row = row0 + r;
        const float* base = (row < N_HALF) ? (src + (size_t)row * K_DIM)
                                           : (tgt + (size_t)(row - N_HALF) * K_DIM);
        s += base[c];
    }
    colpart[(b << 8) + c] = s;
}

// ---------------- bandwidth: sum(d2) = 2m*S - 2*||colsum||^2 ---------------
__global__ void k_stats(const float* __restrict__ sq, const float* __restrict__ colpart,
                        double* __restrict__ band) {
    __shared__ double red[256];
    int t = threadIdx.x;
    double S = 0.0;
    for (int r = t; r < M_TOT; r += 256) S += (double)sq[r];
    red[t] = S;
    __syncthreads();
    for (int off = 128; off > 0; off >>= 1) {
        if (t < off) red[t] += red[t + off];
        __syncthreads();
    }
    double Stot = red[0];
    __syncthreads();
    double cs = 0.0;
    for (int b = 0; b < 32; ++b) cs += (double)colpart[(b << 8) + t];
    red[t] = cs * cs;
    __syncthreads();
    for (int off = 128; off > 0; off >>= 1) {
        if (t < off) red[t] += red[t + off];
        __syncthreads();
    }
    if (t == 0) {
        double sum_d2 = 2.0 * (double)M_TOT * Stot - 2.0 * red[0];
        double bw = sum_d2 / ((double)M_TOT * (double)M_TOT - (double)M_TOT);
        *band = bw * 0.25;   // / KERNEL_MUL^(KERNEL_NUM//2) = 2^2
    }
}

// ---------------- fused pairwise d2 -> 5 gaussians -> signed sum -----------
// 64x64 tile / block, 256 threads (16x16), 4x4 micro-tile per thread.
// LDS [64][64] floats, XOR-swizzled in 16B quads: col quad kq stored at
// kq ^ (row>>2).  Conflict-free ds_read_b128 for both panels.
__global__ __launch_bounds__(256) void k_main(const float* __restrict__ src,
                                              const float* __restrict__ tgt,
                                              const float* __restrict__ sq,
                                              const double* __restrict__ band,
                                              double* __restrict__ acc) {
    int bi = blockIdx.y, bj = blockIdx.x;
    if (bj < bi) return;   // symmetry: upper triangle only

    __shared__ float As[64][64];
    __shared__ float Bs[64][64];
    __shared__ float wpart[4];

    int tid = threadIdx.x;
    int tx = tid & 15, ty = tid >> 4;
    int row0 = bi << 6, col0 = bj << 6;
    const float* abase = (row0 < N_HALF) ? (src + (size_t)row0 * K_DIM)
                                         : (tgt + (size_t)(row0 - N_HALF) * K_DIM);
    const float* bbase = (col0 < N_HALF) ? (src + (size_t)col0 * K_DIM)
                                         : (tgt + (size_t)(col0 - N_HALF) * K_DIM);

    float accm[4][4] = {};

    for (int kc = 0; kc < K_DIM; kc += 64) {
        __syncthreads();   // protect previous iteration's reads
#pragma unroll
        for (int p = 0; p < 4; ++p) {
            int q  = (p << 8) + tid;       // 0..1023
            int r  = q >> 4;               // row 0..63
            int kq = q & 15;               // 16B quad 0..15
            int swz = kq ^ (r >> 2);
            float4 va = *(const float4*)(abase + (size_t)r * K_DIM + kc + (kq << 2));
            *(float4*)&As[r][swz << 2] = va;
            float4 vb = *(const float4*)(bbase + (size_t)r * K_DIM + kc + (kq << 2));
            *(float4*)&Bs[r][swz << 2] = vb;
        }
        __syncthreads();

#pragma unroll
        for (int kq = 0; kq < 16; ++kq) {
            float4 a[4], b[4];
#pragma unroll
            for (int i = 0; i < 4; ++i)
                a[i] = *(const float4*)&As[(ty << 2) + i][(kq ^ ty) << 2];
#pragma unroll
            for (int j = 0; j < 4; ++j)
                b[j] = *(const float4*)&Bs[(tx << 2) + j][(kq ^ tx) << 2];
#pragma unroll
            for (int i = 0; i < 4; ++i)
#pragma unroll
                for (int j = 0; j < 4; ++j)
                    accm[i][j] += a[i].x * b[j].x + a[i].y * b[j].y +
                                  a[i].z * b[j].z + a[i].w * b[j].w;
        }
    }

    // epilogue: d2 -> 5 exp2 -> partial sum
    double bw = *band;
    float e0 = (float)(-1.4426950408889634 / bw);   // -log2(e)/bandwidth
    float srow[4], scol[4];
#pragma unroll
    for (int i = 0; i < 4; ++i) srow[i] = sq[row0 + (ty << 2) + i];
#pragma unroll
    for (int j = 0; j < 4; ++j) scol[j] = sq[col0 + (tx << 2) + j];

    float part = 0.f;
#pragma unroll
    for (int i = 0; i < 4; ++i) {
#pragma unroll
        for (int j = 0; j < 4; ++j) {
            float d2 = srow[i] + scol[j] - 2.f * accm[i][j];
            float c = e0, ks = 0.f;
#pragma unroll
            for (int l = 0; l < 5; ++l) { ks += exp2f(d2 * c); c *= 0.5f; }
            part += ks;
        }
    }

    int lane = tid & 63;
#pragma unroll
    for (int off = 32; off > 0; off >>= 1) part += __shfl_down(part, off, 64);
    if (lane == 0) wpart[tid >> 6] = part;
    __syncthreads();
    if (tid == 0) {
        float sgn = ((row0 < N_HALF) == (col0 < N_HALF)) ? 1.f : -1.f;
        float w   = (bi == bj) ? 1.f : 2.f;
        double tot = ((double)wpart[0] + (double)wpart[1] +
                      (double)wpart[2] + (double)wpart[3]) * (double)(sgn * w);
        atomicAdd(acc, tot);
    }
}

// ---------------- finalize -------------------------------------------------
__global__ void k_final(const double* __restrict__ acc, float* __restrict__ out) {
    out[0] = (float)(*acc * (1.0 / ((double)N_HALF * (double)N_HALF)));
}

extern "C" void kernel_launch(void* const* d_in, const int* in_sizes, int n_in,
                              void* d_out, int out_size, void* d_ws, size_t ws_size,
                              hipStream_t stream) {
    const float* src = (const float*)d_in[0];
    const float* tgt = (const float*)d_in[1];
    float*  sq      = (float*)((char*)d_ws + WS_SQ);
    float*  colpart = (float*)((char*)d_ws + WS_COLPART);
    double* band    = (double*)((char*)d_ws + WS_BAND);
    double* acc     = (double*)((char*)d_ws + WS_ACC);

    hipMemsetAsync(d_ws, 0, WS_BYTES, stream);
    k_rowsq  <<<M_TOT / 4, 256, 0, stream>>>(src, tgt, sq);
    k_colpart<<<32,        256, 0, stream>>>(src, tgt, colpart);
    k_stats  <<<1,         256, 0, stream>>>(sq, colpart, band);
    k_main   <<<dim3(128, 128), 256, 0, stream>>>(src, tgt, sq, band, acc);
    k_final  <<<1, 1, 0, stream>>>(acc, (float*)d_out);
}

// Round 2
// 162.453 us; speedup vs baseline: 4.1522x; 4.1522x over previous
//
#include <hip/hip_runtime.h>
#include <hip/hip_bf16.h>

#define N_HALF 4096
#define M_TOT  8192
#define K_DIM  256
#define KP     768            // packed K = 3*256

// ws layout (bytes)
#define WS_SQ      0                     // 8192 floats
#define WS_COLPART 32768                 // 32*256 floats
#define WS_BAND    65536                 // 1 double
#define WS_ACC     65544                 // 1 double
#define WS_P       131072                // 8192*768 ushort = 12.58 MB
#define WS_Q       (WS_P + (size_t)M_TOT * KP * 2)

typedef __attribute__((ext_vector_type(8))) short short8;
typedef __attribute__((ext_vector_type(4))) float f32x4;

__device__ __forceinline__ void gload16(const void* g, void* l) {
    __builtin_amdgcn_global_load_lds(
        (const __attribute__((address_space(1))) void*)g,
        (__attribute__((address_space(3))) void*)l, 16, 0, 0);
}

// ---------------- row sum-of-squares ----------------
__global__ void k_rowsq(const float* __restrict__ src, const float* __restrict__ tgt,
                        float* __restrict__ sq) {
    int wave = threadIdx.x >> 6, lane = threadIdx.x & 63;
    int row  = (blockIdx.x << 2) + wave;
    const float* base = (row < N_HALF) ? (src + (size_t)row * K_DIM)
                                       : (tgt + (size_t)(row - N_HALF) * K_DIM);
    float4 v = *(const float4*)(base + (lane << 2));
    float s = v.x * v.x + v.y * v.y + v.z * v.z + v.w * v.w;
#pragma unroll
    for (int off = 32; off > 0; off >>= 1) s += __shfl_down(s, off, 64);
    if (lane == 0) sq[row] = s;
}

// ---------------- column partial sums ----------------
__global__ void k_colpart(const float* __restrict__ src, const float* __restrict__ tgt,
                          float* __restrict__ colpart) {
    int c = threadIdx.x;
    int b = blockIdx.x;
    int row0 = b << 8;
    float s = 0.f;
    for (int r = 0; r < 256; ++r) {
        int row = row0 + r;
        const float* base = (row < N_HALF) ? (src + (size_t)row * K_DIM)
                                           : (tgt + (size_t)(row - N_HALF) * K_DIM);
        s += base[c];
    }
    colpart[(b << 8) + c] = s;
}

// ---------------- bandwidth ----------------
__global__ void k_stats(const float* __restrict__ sq, const float* __restrict__ colpart,
                        double* __restrict__ band) {
    __shared__ double red[256];
    int t = threadIdx.x;
    double S = 0.0;
    for (int r = t; r < M_TOT; r += 256) S += (double)sq[r];
    red[t] = S;
    __syncthreads();
    for (int off = 128; off > 0; off >>= 1) {
        if (t < off) red[t] += red[t + off];
        __syncthreads();
    }
    double Stot = red[0];
    __syncthreads();
    double cs = 0.0;
    for (int b = 0; b < 32; ++b) cs += (double)colpart[(b << 8) + t];
    red[t] = cs * cs;
    __syncthreads();
    for (int off = 128; off > 0; off >>= 1) {
        if (t < off) red[t] += red[t + off];
        __syncthreads();
    }
    if (t == 0) {
        double sum_d2 = 2.0 * (double)M_TOT * Stot - 2.0 * red[0];
        double bw = sum_d2 / ((double)M_TOT * (double)M_TOT - (double)M_TOT);
        *band = bw * 0.25;
    }
}

// ---------------- split-pack: P=[hi,hi,lo], Q=[hi,lo,hi] -------------------
__global__ void k_pack(const float* __restrict__ src, const float* __restrict__ tgt,
                       ushort* __restrict__ P, ushort* __restrict__ Q) {
    int tid = threadIdx.x;
    int row = (blockIdx.x << 2) + (tid >> 6);
    int lane = tid & 63;
    const float* base = (row < N_HALF) ? (src + (size_t)row * K_DIM)
                                       : (tgt + (size_t)(row - N_HALF) * K_DIM);
    float4 v = *(const float4*)(base + (lane << 2));
    float f[4] = {v.x, v.y, v.z, v.w};
    ushort h[4], lo[4];
#pragma unroll
    for (int c = 0; c < 4; ++c) {
        __hip_bfloat16 hb = __float2bfloat16(f[c]);
        float hf = __bfloat162float(hb);
        __hip_bfloat16 lb = __float2bfloat16(f[c] - hf);
        h[c]  = *(ushort*)&hb;
        lo[c] = *(ushort*)&lb;
    }
    ushort4 hv = {h[0], h[1], h[2], h[3]};
    ushort4 lv = {lo[0], lo[1], lo[2], lo[3]};
    size_t rb = (size_t)row * KP + (lane << 2);
    *(ushort4*)(P + rb)       = hv;
    *(ushort4*)(P + rb + 256) = hv;
    *(ushort4*)(P + rb + 512) = lv;
    *(ushort4*)(Q + rb)       = hv;
    *(ushort4*)(Q + rb + 256) = lv;
    *(ushort4*)(Q + rb + 512) = hv;
}

// ---------------- fused MFMA: G tile -> d2 -> 5 gaussians -> signed sum ----
// 128x128 tile, 4 waves (2x2), 16x16x32 bf16 MFMA, BK=64, K=768.
// LDS linear [128][64] ushort; chunk swizzle c ^= (row&7) applied on the
// global SOURCE address (global_load_lds dest must stay linear) and on the
// ds_read address.
__global__ __launch_bounds__(256) void k_mmd(const ushort* __restrict__ P,
                                             const ushort* __restrict__ Q,
                                             const float* __restrict__ sq,
                                             const double* __restrict__ band,
                                             double* __restrict__ acc) {
    // triangle decode: block t -> (bi, bj), bi <= bj, 64x64 tiles
    int t = blockIdx.x;
    int bi = (int)(64.5 - sqrt(64.5 * 64.5 - 2.0 * (double)t));
    while (bi * 64 - bi * (bi - 1) / 2 > t) --bi;
    while ((bi + 1) * 64 - (bi + 1) * bi / 2 <= t) ++bi;
    int bj = bi + (t - (bi * 64 - bi * (bi - 1) / 2));

    __shared__ ushort As[128][64];
    __shared__ ushort Bs[128][64];
    __shared__ float sqr[128], sqc[128];
    __shared__ float wpart[4];

    int tid = threadIdx.x, lane = tid & 63, w = tid >> 6;
    int wr = w >> 1, wc = w & 1;
    int row0 = bi << 7, col0 = bj << 7;

    const ushort* Pb = P + (size_t)row0 * KP;
    const ushort* Qb = Q + (size_t)col0 * KP;

    f32x4 accm[4][4] = {};

    // staging geometry: chunk q = p*256 + tid; lds row = q>>3, chunk col = q&7
    int sr = tid >> 3;             // + p*32
    int scb = tid & 7;

    for (int kc = 0; kc < KP; kc += 64) {
        __syncthreads();
#pragma unroll
        for (int p = 0; p < 4; ++p) {
            int r  = (p << 5) + sr;
            int sc = scb ^ (r & 7);
            gload16(Pb + (size_t)r * KP + kc + (sc << 3),
                    (char*)&As[0][0] + (((p << 2) + w) << 10));
            gload16(Qb + (size_t)r * KP + kc + (sc << 3),
                    (char*)&Bs[0][0] + (((p << 2) + w) << 10));
        }
        __syncthreads();

#pragma unroll
        for (int kk = 0; kk < 2; ++kk) {
            short8 af[4], bf[4];
#pragma unroll
            for (int m = 0; m < 4; ++m) {
                int r  = (wr << 6) + (m << 4) + (lane & 15);
                int ch = ((kk << 2) + (lane >> 4)) ^ (r & 7);
                af[m] = *(const short8*)&As[r][ch << 3];
            }
#pragma unroll
            for (int n = 0; n < 4; ++n) {
                int r  = (wc << 6) + (n << 4) + (lane & 15);
                int ch = ((kk << 2) + (lane >> 4)) ^ (r & 7);
                bf[n] = *(const short8*)&Bs[r][ch << 3];
            }
#pragma unroll
            for (int m = 0; m < 4; ++m)
#pragma unroll
                for (int n = 0; n < 4; ++n)
                    accm[m][n] = __builtin_amdgcn_mfma_f32_16x16x32_bf16(
                        af[m], bf[n], accm[m][n], 0, 0, 0);
        }
    }

    __syncthreads();
    if (tid < 128) sqr[tid] = sq[row0 + tid];
    else           sqc[tid - 128] = sq[col0 + tid - 128];
    __syncthreads();

    double bwd = *band;
    float e0 = (float)(-1.4426950408889634 / bwd);   // -log2(e)/bandwidth

    float part = 0.f;
#pragma unroll
    for (int m = 0; m < 4; ++m) {
#pragma unroll
        for (int n = 0; n < 4; ++n) {
#pragma unroll
            for (int j = 0; j < 4; ++j) {
                float g  = accm[m][n][j];
                int rl = (wr << 6) + (m << 4) + ((lane >> 4) << 2) + j;
                int cl = (wc << 6) + (n << 4) + (lane & 15);
                float d2 = sqr[rl] + sqc[cl] - 2.f * g;
                float c = e0;
#pragma unroll
                for (int l = 0; l < 5; ++l) { part += exp2f(d2 * c); c *= 0.5f; }
            }
        }
    }

#pragma unroll
    for (int off = 32; off > 0; off >>= 1) part += __shfl_down(part, off, 64);
    if (lane == 0) wpart[w] = part;
    __syncthreads();
    if (tid == 0) {
        float sgn = ((row0 < N_HALF) == (col0 < N_HALF)) ? 1.f : -1.f;
        float wt  = (bi == bj) ? 1.f : 2.f;
        double tot = ((double)wpart[0] + (double)wpart[1] +
                      (double)wpart[2] + (double)wpart[3]) * (double)(sgn * wt);
        atomicAdd(acc, tot);
    }
}

// ---------------- finalize ----------------
__global__ void k_final(const double* __restrict__ acc, float* __restrict__ out) {
    out[0] = (float)(*acc * (1.0 / ((double)N_HALF * (double)N_HALF)));
}

extern "C" void kernel_launch(void* const* d_in, const int* in_sizes, int n_in,
                              void* d_out, int out_size, void* d_ws, size_t ws_size,
                              hipStream_t stream) {
    const float* src = (const float*)d_in[0];
    const float* tgt = (const float*)d_in[1];
    float*  sq      = (float*)((char*)d_ws + WS_SQ);
    float*  colpart = (float*)((char*)d_ws + WS_COLPART);
    double* band    = (double*)((char*)d_ws + WS_BAND);
    double* acc     = (double*)((char*)d_ws + WS_ACC);
    ushort* P       = (ushort*)((char*)d_ws + WS_P);
    ushort* Q       = (ushort*)((char*)d_ws + WS_Q);

    hipMemsetAsync(d_ws, 0, 65552, stream);
    k_pack   <<<M_TOT / 4, 256, 0, stream>>>(src, tgt, P, Q);
    k_rowsq  <<<M_TOT / 4, 256, 0, stream>>>(src, tgt, sq);
    k_colpart<<<32,        256, 0, stream>>>(src, tgt, colpart);
    k_stats  <<<1,         256, 0, stream>>>(sq, colpart, band);
    k_mmd    <<<2080,      256, 0, stream>>>(P, Q, sq, band, acc);
    k_final  <<<1, 1, 0, stream>>>(acc, (float*)d_out);
}

// Round 3
// 138.404 us; speedup vs baseline: 4.8736x; 1.1738x over previous
//
#include <hip/hip_runtime.h>
#include <hip/hip_bf16.h>

#define N_HALF 4096
#define M_TOT  8192
#define K_DIM  256
#define KP     768            // packed K = 3*256

// ws layout (bytes)
#define WS_SQ      0                     // 8192 floats (32 KB)
#define WS_COLPART 32768                 // 256*256 floats (256 KB)
#define WS_BAND    294912                // 1 double
#define WS_ACC     294920                // 1 double
#define WS_P       327680                // 8192*768 ushort = 12.58 MB
#define WS_Q       (WS_P + (size_t)M_TOT * KP * 2)

typedef __attribute__((ext_vector_type(8))) short short8;
typedef __attribute__((ext_vector_type(4))) float f32x4;

__device__ __forceinline__ void gload16(const void* g, void* l) {
    __builtin_amdgcn_global_load_lds(
        (const __attribute__((address_space(1))) void*)g,
        (__attribute__((address_space(3))) void*)l, 16, 0, 0);
}

// ------- pack (split hi/lo) + row sum-of-squares, one pass over input -------
__global__ void k_pack(const float* __restrict__ src, const float* __restrict__ tgt,
                       ushort* __restrict__ P, ushort* __restrict__ Q,
                       float* __restrict__ sq) {
    int tid = threadIdx.x;
    int row = (blockIdx.x << 2) + (tid >> 6);
    int lane = tid & 63;
    const float* base = (row < N_HALF) ? (src + (size_t)row * K_DIM)
                                       : (tgt + (size_t)(row - N_HALF) * K_DIM);
    float4 v = *(const float4*)(base + (lane << 2));
    float f[4] = {v.x, v.y, v.z, v.w};
    ushort h[4], lo[4];
#pragma unroll
    for (int c = 0; c < 4; ++c) {
        __hip_bfloat16 hb = __float2bfloat16(f[c]);
        float hf = __bfloat162float(hb);
        __hip_bfloat16 lb = __float2bfloat16(f[c] - hf);
        h[c]  = *(ushort*)&hb;
        lo[c] = *(ushort*)&lb;
    }
    ushort4 hv = {h[0], h[1], h[2], h[3]};
    ushort4 lv = {lo[0], lo[1], lo[2], lo[3]};
    size_t rb = (size_t)row * KP + (lane << 2);
    *(ushort4*)(P + rb)       = hv;
    *(ushort4*)(P + rb + 256) = hv;
    *(ushort4*)(P + rb + 512) = lv;
    *(ushort4*)(Q + rb)       = hv;
    *(ushort4*)(Q + rb + 256) = lv;
    *(ushort4*)(Q + rb + 512) = hv;

    float s = v.x * v.x + v.y * v.y + v.z * v.z + v.w * v.w;
#pragma unroll
    for (int off = 32; off > 0; off >>= 1) s += __shfl_down(s, off, 64);
    if (lane == 0) sq[row] = s;
}

// ---------------- column partial sums: 256 blocks x 32 rows ----------------
__global__ void k_colpart(const float* __restrict__ src, const float* __restrict__ tgt,
                          float* __restrict__ colpart) {
    int c = threadIdx.x;
    int row0 = blockIdx.x << 5;
    float s = 0.f;
#pragma unroll 4
    for (int r = 0; r < 32; ++r) {
        int row = row0 + r;
        const float* base = (row < N_HALF) ? (src + (size_t)row * K_DIM)
                                           : (tgt + (size_t)(row - N_HALF) * K_DIM);
        s += base[c];
    }
    colpart[(blockIdx.x << 8) + c] = s;
}

// ---------------- bandwidth ----------------
__global__ void k_stats(const float* __restrict__ sq, const float* __restrict__ colpart,
                        double* __restrict__ band) {
    __shared__ double red[256];
    int t = threadIdx.x;
    double S = 0.0;
    for (int r = t; r < M_TOT; r += 256) S += (double)sq[r];
    red[t] = S;
    __syncthreads();
    for (int off = 128; off > 0; off >>= 1) {
        if (t < off) red[t] += red[t + off];
        __syncthreads();
    }
    double Stot = red[0];
    __syncthreads();
    double cs = 0.0;
    for (int b = 0; b < 256; ++b) cs += (double)colpart[(b << 8) + t];
    red[t] = cs * cs;
    __syncthreads();
    for (int off = 128; off > 0; off >>= 1) {
        if (t < off) red[t] += red[t + off];
        __syncthreads();
    }
    if (t == 0) {
        double sum_d2 = 2.0 * (double)M_TOT * Stot - 2.0 * red[0];
        double bw = sum_d2 / ((double)M_TOT * (double)M_TOT - (double)M_TOT);
        *band = bw * 0.25;
    }
}

// ---------------- fused MFMA: G tile -> d2 -> 5 gaussians -> signed sum ----
// 128x128 tile, 4 waves (2x2), 16x16x32 bf16 MFMA, BK=64, K=768.
__global__ __launch_bounds__(256) void k_mmd(const ushort* __restrict__ P,
                                             const ushort* __restrict__ Q,
                                             const float* __restrict__ sq,
                                             const double* __restrict__ band,
                                             double* __restrict__ acc) {
    // XCD-aware swizzle (2080 % 8 == 0, 260 blocks per XCD chunk)
    int raw = blockIdx.x;
    int t = (raw & 7) * 260 + (raw >> 3);

    // triangle decode: t -> (bi, bj), bi <= bj over 64x64 tile grid
    int bi = (int)(64.5 - sqrt(64.5 * 64.5 - 2.0 * (double)t));
    while (bi * 64 - bi * (bi - 1) / 2 > t) --bi;
    while ((bi + 1) * 64 - (bi + 1) * bi / 2 <= t) ++bi;
    int bj = bi + (t - (bi * 64 - bi * (bi - 1) / 2));

    __shared__ ushort As[128][64];
    __shared__ ushort Bs[128][64];
    __shared__ float sqr[128], sqc[128];
    __shared__ float wpart[4];

    int tid = threadIdx.x, lane = tid & 63, w = tid >> 6;
    int wr = w >> 1, wc = w & 1;
    int row0 = bi << 7, col0 = bj << 7;

    // stage sq tiles early; main-loop barriers order these before epilogue use
    if (tid < 128) sqr[tid] = sq[row0 + tid];
    else           sqc[tid - 128] = sq[col0 + tid - 128];
    double bwd = *band;

    const ushort* Pb = P + (size_t)row0 * KP;
    const ushort* Qb = Q + (size_t)col0 * KP;

    f32x4 accm[4][4] = {};

    int sr = tid >> 3;             // + p*32
    int scb = tid & 7;

    for (int kc = 0; kc < KP; kc += 64) {
        __syncthreads();
#pragma unroll
        for (int p = 0; p < 4; ++p) {
            int r  = (p << 5) + sr;
            int sc = scb ^ (r & 7);
            gload16(Pb + (size_t)r * KP + kc + (sc << 3),
                    (char*)&As[0][0] + (((p << 2) + w) << 10));
            gload16(Qb + (size_t)r * KP + kc + (sc << 3),
                    (char*)&Bs[0][0] + (((p << 2) + w) << 10));
        }
        __syncthreads();

#pragma unroll
        for (int kk = 0; kk < 2; ++kk) {
            short8 af[4], bf[4];
#pragma unroll
            for (int m = 0; m < 4; ++m) {
                int r  = (wr << 6) + (m << 4) + (lane & 15);
                int ch = ((kk << 2) + (lane >> 4)) ^ (r & 7);
                af[m] = *(const short8*)&As[r][ch << 3];
            }
#pragma unroll
            for (int n = 0; n < 4; ++n) {
                int r  = (wc << 6) + (n << 4) + (lane & 15);
                int ch = ((kk << 2) + (lane >> 4)) ^ (r & 7);
                bf[n] = *(const short8*)&Bs[r][ch << 3];
            }
#pragma unroll
            for (int m = 0; m < 4; ++m)
#pragma unroll
                for (int n = 0; n < 4; ++n)
                    accm[m][n] = __builtin_amdgcn_mfma_f32_16x16x32_bf16(
                        af[m], bf[n], accm[m][n], 0, 0, 0);
        }
    }

    // ---- epilogue: q = -(d2)*E16; t4=exp2(q); squarings give the 5 terms ---
    float E16 = (float)(1.4426950408889634 / (bwd * 16.0));   // log2e/(16*bw)
    float twoE16 = 2.f * E16;

    float A4[4][4];   // -sqr[rl]*E16, rl = wr*64 + m*16 + (lane>>4)*4 + j
    float Bv[4];      // -sqc[cl]*E16, cl = wc*64 + n*16 + (lane&15)
#pragma unroll
    for (int m = 0; m < 4; ++m) {
        f32x4 v = *(const f32x4*)&sqr[(wr << 6) + (m << 4) + ((lane >> 4) << 2)];
#pragma unroll
        for (int j = 0; j < 4; ++j) A4[m][j] = -v[j] * E16;
    }
#pragma unroll
    for (int n = 0; n < 4; ++n)
        Bv[n] = -sqc[(wc << 6) + (n << 4) + (lane & 15)] * E16;

    float p0 = 0.f, p1 = 0.f, p2 = 0.f, p3 = 0.f, p4 = 0.f;
#pragma unroll
    for (int m = 0; m < 4; ++m) {
#pragma unroll
        for (int n = 0; n < 4; ++n) {
#pragma unroll
            for (int j = 0; j < 4; ++j) {
                float g = accm[m][n][j];
                float q = fmaf(g, twoE16, A4[m][j] + Bv[n]);  // = -d2*E16
                float t4 = exp2f(q);
                float t3 = t4 * t4;
                float t2 = t3 * t3;
                float t1 = t2 * t2;
                float t0 = t1 * t1;
                p4 += t4; p3 += t3; p2 += t2; p1 += t1; p0 += t0;
            }
        }
    }
    float part = (p0 + p1) + (p2 + p3) + p4;

#pragma unroll
    for (int off = 32; off > 0; off >>= 1) part += __shfl_down(part, off, 64);
    if (lane == 0) wpart[w] = part;
    __syncthreads();
    if (tid == 0) {
        float sgn = ((row0 < N_HALF) == (col0 < N_HALF)) ? 1.f : -1.f;
        float wt  = (bi == bj) ? 1.f : 2.f;
        double tot = ((double)wpart[0] + (double)wpart[1] +
                      (double)wpart[2] + (double)wpart[3]) * (double)(sgn * wt);
        atomicAdd(acc, tot);
    }
}

// ---------------- finalize ----------------
__global__ void k_final(const double* __restrict__ acc, float* __restrict__ out) {
    out[0] = (float)(*acc * (1.0 / ((double)N_HALF * (double)N_HALF)));
}

extern "C" void kernel_launch(void* const* d_in, const int* in_sizes, int n_in,
                              void* d_out, int out_size, void* d_ws, size_t ws_size,
                              hipStream_t stream) {
    const float* src = (const float*)d_in[0];
    const float* tgt = (const float*)d_in[1];
    float*  sq      = (float*)((char*)d_ws + WS_SQ);
    float*  colpart = (float*)((char*)d_ws + WS_COLPART);
    double* band    = (double*)((char*)d_ws + WS_BAND);
    double* acc     = (double*)((char*)d_ws + WS_ACC);
    ushort* P       = (ushort*)((char*)d_ws + WS_P);
    ushort* Q       = (ushort*)((char*)d_ws + WS_Q);

    hipMemsetAsync((char*)d_ws + WS_BAND, 0, 16, stream);
    k_pack   <<<M_TOT / 4, 256, 0, stream>>>(src, tgt, P, Q, sq);
    k_colpart<<<256,       256, 0, stream>>>(src, tgt, colpart);
    k_stats  <<<1,         256, 0, stream>>>(sq, colpart, band);
    k_mmd    <<<2080,      256, 0, stream>>>(P, Q, sq, band, acc);
    k_final  <<<1, 1, 0, stream>>>(acc, (float*)d_out);
}

// Round 4
// 107.612 us; speedup vs baseline: 6.2682x; 1.2861x over previous
//
#include <hip/hip_runtime.h>
#include <hip/hip_bf16.h>

#define N_HALF 4096
#define M_TOT  8192
#define K_DIM  256
#define NTILE  2080    // triangle tiles over 64x64 grid of 128-tiles

// ws layout (bytes)
#define WS_SQ      0                       // 8192 f32 (32 KB)
#define WS_COLPART 32768                   // 256*256 f32 (256 KB)
#define WS_BAND    (32768 + 262144)        // double
#define WS_ACC     (WS_BAND + 8)           // double
#define WS_CNT     (WS_BAND + 16)          // uint
#define WS_P       (WS_BAND + 64)          // 8192*256 bf16 = 4 MB

typedef __attribute__((ext_vector_type(8))) short short8;
typedef __attribute__((ext_vector_type(4))) float f32x4;

__device__ __forceinline__ void gload16(const void* g, void* l) {
    __builtin_amdgcn_global_load_lds(
        (const __attribute__((address_space(1))) void*)g,
        (__attribute__((address_space(3))) void*)l, 16, 0, 0);
}

// ---- pack bf16 + row sum-of-squares + column partial sums, one input pass ----
__global__ __launch_bounds__(256) void k_pack(const float* __restrict__ src,
        const float* __restrict__ tgt, ushort* __restrict__ P,
        float* __restrict__ sq, float* __restrict__ colpart) {
    __shared__ float colred[4][256];
    int tid = threadIdx.x, w = tid >> 6, l = tid & 63;
    int blk = blockIdx.x;
    float c0 = 0.f, c1 = 0.f, c2 = 0.f, c3 = 0.f;
#pragma unroll
    for (int j = 0; j < 8; ++j) {
        int row = (blk << 5) + (j << 2) + w;
        const float* base = (row < N_HALF) ? src + (size_t)row * K_DIM
                                           : tgt + (size_t)(row - N_HALF) * K_DIM;
        float4 v = *(const float4*)(base + (l << 2));
        __hip_bfloat16 b0 = __float2bfloat16(v.x), b1 = __float2bfloat16(v.y),
                       b2 = __float2bfloat16(v.z), b3 = __float2bfloat16(v.w);
        ushort4 hv = { *(ushort*)&b0, *(ushort*)&b1, *(ushort*)&b2, *(ushort*)&b3 };
        *(ushort4*)(P + (size_t)row * K_DIM + (l << 2)) = hv;
        float s = v.x * v.x + v.y * v.y + v.z * v.z + v.w * v.w;
#pragma unroll
        for (int off = 32; off > 0; off >>= 1) s += __shfl_down(s, off, 64);
        if (l == 0) sq[row] = s;
        c0 += v.x; c1 += v.y; c2 += v.z; c3 += v.w;
    }
    *(float4*)&colred[w][l << 2] = make_float4(c0, c1, c2, c3);
    __syncthreads();
    colpart[(blk << 8) + tid] = colred[0][tid] + colred[1][tid] +
                                colred[2][tid] + colred[3][tid];
}

// ---------------- bandwidth ----------------
__global__ void k_stats(const float* __restrict__ sq, const float* __restrict__ colpart,
                        double* __restrict__ band) {
    __shared__ double red[256];
    int t = threadIdx.x;
    double S = 0.0;
    for (int r = t; r < M_TOT; r += 256) S += (double)sq[r];
    red[t] = S;
    __syncthreads();
    for (int off = 128; off > 0; off >>= 1) {
        if (t < off) red[t] += red[t + off];
        __syncthreads();
    }
    double Stot = red[0];
    __syncthreads();
    double cs = 0.0;
    for (int b = 0; b < 256; ++b) cs += (double)colpart[(b << 8) + t];
    red[t] = cs * cs;
    __syncthreads();
    for (int off = 128; off > 0; off >>= 1) {
        if (t < off) red[t] += red[t + off];
        __syncthreads();
    }
    if (t == 0) {
        double sum_d2 = 2.0 * (double)M_TOT * Stot - 2.0 * red[0];
        double bw = sum_d2 / ((double)M_TOT * (double)M_TOT - (double)M_TOT);
        *band = bw * 0.25;
    }
}

// ---- fused MFMA tile -> d2 -> 5 gaussians -> signed sum (+ folded finalize) ----
// 128x128 tile, 512 thr (8 waves 2x4, per-wave 64x32), K=256, BK=64,
// double-buffered 64 KB LDS, stage(t+1) overlapped with compute(t).
__global__ __launch_bounds__(512, 4) void k_mmd(const ushort* __restrict__ P,
        const float* __restrict__ sq, const double* __restrict__ band,
        double* __restrict__ acc, unsigned int* __restrict__ cnt,
        float* __restrict__ out) {
    // XCD-aware swizzle (2080 = 8 * 260, bijective)
    int raw = blockIdx.x;
    int t = (raw & 7) * 260 + (raw >> 3);
    // triangle decode: t -> (bi, bj), bi <= bj over 64x64 tile grid
    int bi = (int)(64.5 - sqrt(64.5 * 64.5 - 2.0 * (double)t));
    while (bi * 64 - bi * (bi - 1) / 2 > t) --bi;
    while ((bi + 1) * 64 - (bi + 1) * bi / 2 <= t) ++bi;
    int bj = bi + (t - (bi * 64 - bi * (bi - 1) / 2));

    __shared__ ushort As[2][128][64];
    __shared__ ushort Bs[2][128][64];

    int tid = threadIdx.x, lane = tid & 63, w = tid >> 6;
    int wr = w >> 2, wc = w & 3;
    int row0 = bi << 7, col0 = bj << 7;
    const ushort* Pa = P + (size_t)row0 * K_DIM;
    const ushort* Pb = P + (size_t)col0 * K_DIM;

    double bwd = *band;

    // hoisted fragment LDS byte-offsets; per-kk address = off ^ (kk<<6)
    int chunk0 = ((lane >> 4) ^ (lane & 7)) << 4;
    int aoff[4], boff[2];
#pragma unroll
    for (int m = 0; m < 4; ++m)
        aoff[m] = (((wr << 6) + (m << 4) + (lane & 15)) << 7) + chunk0;
#pragma unroll
    for (int n = 0; n < 2; ++n)
        boff[n] = (((wc << 5) + (n << 4) + (lane & 15)) << 7) + chunk0;

    // staging geometry: row rr (+p*64), swizzled 16B chunk, linear LDS dest
    int rr = tid >> 3;
    int sc = (tid & 7) ^ (rr & 7);
    size_t soff = (size_t)rr * K_DIM + (sc << 3);
    int ldst = tid << 4;

    f32x4 accm[4][2] = {};

    // prologue: stage buf0 (kc = 0)
#pragma unroll
    for (int p = 0; p < 2; ++p) {
        gload16(Pa + soff + (p << 14), (char*)&As[0][0][0] + (p << 13) + ldst);
        gload16(Pb + soff + (p << 14), (char*)&Bs[0][0][0] + (p << 13) + ldst);
    }
    __syncthreads();   // waits vmcnt(0): buf0 resident

#pragma unroll
    for (int it = 0; it < 4; ++it) {
        int cur = it & 1;
        if (it < 3) {          // overlap: stage next tile into the other buffer
            int kc = (it + 1) << 6;
#pragma unroll
            for (int p = 0; p < 2; ++p) {
                gload16(Pa + soff + kc + (p << 14),
                        (char*)&As[cur ^ 1][0][0] + (p << 13) + ldst);
                gload16(Pb + soff + kc + (p << 14),
                        (char*)&Bs[cur ^ 1][0][0] + (p << 13) + ldst);
            }
        }
        const char* Ab = (const char*)&As[cur][0][0];
        const char* Bb = (const char*)&Bs[cur][0][0];
#pragma unroll
        for (int kk = 0; kk < 2; ++kk) {
            short8 af[4], bf2[2];
#pragma unroll
            for (int m = 0; m < 4; ++m)
                af[m] = *(const short8*)(Ab + (aoff[m] ^ (kk << 6)));
#pragma unroll
            for (int n = 0; n < 2; ++n)
                bf2[n] = *(const short8*)(Bb + (boff[n] ^ (kk << 6)));
#pragma unroll
            for (int m = 0; m < 4; ++m)
#pragma unroll
                for (int n = 0; n < 2; ++n)
                    accm[m][n] = __builtin_amdgcn_mfma_f32_16x16x32_bf16(
                        af[m], bf2[n], accm[m][n], 0, 0, 0);
        }
        __syncthreads();   // drains staged loads; WAR-protects buffer reuse
    }

    // ---- epilogue: q = -d2*E16; t4=exp2(q); squarings give all 5 terms ----
    bool isdiag = (bi == bj);
    float E16 = (float)(1.4426950408889634 / (bwd * 16.0));
    float twoE16 = 2.f * E16;

    float A4[4][4];
#pragma unroll
    for (int m = 0; m < 4; ++m) {
        float4 v = *(const float4*)&sq[row0 + (wr << 6) + (m << 4) + ((lane >> 4) << 2)];
        A4[m][0] = -v.x * E16; A4[m][1] = -v.y * E16;
        A4[m][2] = -v.z * E16; A4[m][3] = -v.w * E16;
    }
    float Bv[2];
#pragma unroll
    for (int n = 0; n < 2; ++n)
        Bv[n] = -sq[col0 + (wc << 5) + (n << 4) + (lane & 15)] * E16;

    float p0 = 0.f, p1 = 0.f, p2 = 0.f, p3 = 0.f, p4 = 0.f;
#pragma unroll
    for (int m = 0; m < 4; ++m)
#pragma unroll
    for (int n = 0; n < 2; ++n) {
        int rlb = (wr << 6) + (m << 4) + ((lane >> 4) << 2);
        int cl  = (wc << 5) + (n << 4) + (lane & 15);
#pragma unroll
        for (int j = 0; j < 4; ++j) {
            float q = fmaf(accm[m][n][j], twoE16, A4[m][j] + Bv[n]);
            if (isdiag && (rlb + j == cl)) q = 0.f;   // exact-zero diagonal
            float t4 = exp2f(q);
            float t3 = t4 * t4, t2 = t3 * t3, t1 = t2 * t2, t0 = t1 * t1;
            p4 += t4; p3 += t3; p2 += t2; p1 += t1; p0 += t0;
        }
    }
    float part = (p0 + p1) + (p2 + p3) + p4;
#pragma unroll
    for (int off = 32; off > 0; off >>= 1) part += __shfl_down(part, off, 64);

    float* wpart = (float*)&As[0][0][0];   // LDS dead after main loop
    if (lane == 0) wpart[w] = part;
    __syncthreads();
    if (tid == 0) {
        float sgn = ((row0 < N_HALF) == (col0 < N_HALF)) ? 1.f : -1.f;
        float wt  = isdiag ? 1.f : 2.f;
        double tot = 0.0;
#pragma unroll
        for (int i = 0; i < 8; ++i) tot += (double)wpart[i];
        atomicAdd(acc, tot * (double)(sgn * wt));
        __threadfence();
        unsigned int old = atomicAdd(cnt, 1u);
        if (old == NTILE - 1) {   // last block finalizes (folded k_final)
            double a = atomicAdd(acc, 0.0);
            out[0] = (float)(a * (1.0 / ((double)N_HALF * (double)N_HALF)));
        }
    }
}

extern "C" void kernel_launch(void* const* d_in, const int* in_sizes, int n_in,
                              void* d_out, int out_size, void* d_ws, size_t ws_size,
                              hipStream_t stream) {
    const float* src = (const float*)d_in[0];
    const float* tgt = (const float*)d_in[1];
    float*  sq      = (float*)((char*)d_ws + WS_SQ);
    float*  colpart = (float*)((char*)d_ws + WS_COLPART);
    double* band    = (double*)((char*)d_ws + WS_BAND);
    double* acc     = (double*)((char*)d_ws + WS_ACC);
    unsigned int* cnt = (unsigned int*)((char*)d_ws + WS_CNT);
    ushort* P       = (ushort*)((char*)d_ws + WS_P);

    hipMemsetAsync((char*)d_ws + WS_BAND, 0, 64, stream);
    k_pack <<<256,   256, 0, stream>>>(src, tgt, P, sq, colpart);
    k_stats<<<1,     256, 0, stream>>>(sq, colpart, band);
    k_mmd  <<<NTILE, 512, 0, stream>>>(P, sq, band, acc, cnt, (float*)d_out);
}

// Round 5
// 100.685 us; speedup vs baseline: 6.6994x; 1.0688x over previous
//
#include <hip/hip_runtime.h>
#include <hip/hip_bf16.h>

#define N_HALF 4096
#define M_TOT  8192
#define K_DIM  256
#define NTILE  2080    // triangle tiles over 64x64 grid of 128-tiles

// ws layout (bytes)
#define WS_SQ      0                       // 8192 f32 (32 KB)
#define WS_COLPART 32768                   // 256*256 f32 (256 KB)
#define WS_SQD     294912                  // 256 f64 (2 KB)
#define WS_BAND    296960                  // f64
#define WS_CNT     296968                  // u32 (k_mmd completion)
#define WS_PCNT    296972                  // u32 (k_pack completion)
#define WS_PARTS   297024                  // 2080 f64 (16640 B)
#define WS_P       313856                  // 8192*256 bf16 = 4 MB

typedef __attribute__((ext_vector_type(8))) short short8;
typedef __attribute__((ext_vector_type(4))) float f32x4;

__device__ __forceinline__ void gload16(const void* g, void* l) {
    __builtin_amdgcn_global_load_lds(
        (const __attribute__((address_space(1))) void*)g,
        (__attribute__((address_space(3))) void*)l, 16, 0, 0);
}

// ---- pack bf16 + row sumsq + col partial sums + (last block) bandwidth ----
__global__ __launch_bounds__(256) void k_pack(const float* __restrict__ src,
        const float* __restrict__ tgt, ushort* __restrict__ P,
        float* __restrict__ sq, float* __restrict__ colpart,
        double* __restrict__ sqd, double* __restrict__ band,
        unsigned int* __restrict__ pcnt) {
    __shared__ float  colred[4][256];
    __shared__ double sblk[4];
    __shared__ double dred[256];
    __shared__ int    lastf;
    int tid = threadIdx.x, w = tid >> 6, l = tid & 63;
    int blk = blockIdx.x;
    float c0 = 0.f, c1 = 0.f, c2 = 0.f, c3 = 0.f;
    double sacc = 0.0;
#pragma unroll
    for (int j = 0; j < 8; ++j) {
        int row = (blk << 5) + (j << 2) + w;
        const float* base = (row < N_HALF) ? src + (size_t)row * K_DIM
                                           : tgt + (size_t)(row - N_HALF) * K_DIM;
        float4 v = *(const float4*)(base + (l << 2));
        __hip_bfloat16 b0 = __float2bfloat16(v.x), b1 = __float2bfloat16(v.y),
                       b2 = __float2bfloat16(v.z), b3 = __float2bfloat16(v.w);
        ushort4 hv = { *(ushort*)&b0, *(ushort*)&b1, *(ushort*)&b2, *(ushort*)&b3 };
        *(ushort4*)(P + (size_t)row * K_DIM + (l << 2)) = hv;
        float s = v.x * v.x + v.y * v.y + v.z * v.z + v.w * v.w;
#pragma unroll
        for (int off = 32; off > 0; off >>= 1) s += __shfl_down(s, off, 64);
        if (l == 0) { sq[row] = s; sacc += (double)s; }
        c0 += v.x; c1 += v.y; c2 += v.z; c3 += v.w;
    }
    *(float4*)&colred[w][l << 2] = make_float4(c0, c1, c2, c3);
    if (l == 0) sblk[w] = sacc;
    __syncthreads();
    colpart[(blk << 8) + tid] = colred[0][tid] + colred[1][tid] +
                                colred[2][tid] + colred[3][tid];
    if (tid == 0) {
        sqd[blk] = sblk[0] + sblk[1] + sblk[2] + sblk[3];
        __threadfence();
        unsigned int o = atomicAdd(pcnt, 1u);
        lastf = (o == 255u);
    }
    __syncthreads();
    if (lastf) {                       // folded k_stats (block-uniform branch)
        __threadfence();
        // Stot
        dred[tid] = sqd[tid];
        __syncthreads();
        for (int off = 128; off > 0; off >>= 1) {
            if (tid < off) dred[tid] += dred[tid + off];
            __syncthreads();
        }
        double Stot = dred[0];
        __syncthreads();
        // ||colsum||^2
        double cs = 0.0;
        for (int b = 0; b < 256; ++b) cs += (double)colpart[(b << 8) + tid];
        dred[tid] = cs * cs;
        __syncthreads();
        for (int off = 128; off > 0; off >>= 1) {
            if (tid < off) dred[tid] += dred[tid + off];
            __syncthreads();
        }
        if (tid == 0) {
            double sum_d2 = 2.0 * (double)M_TOT * Stot - 2.0 * dred[0];
            double bw = sum_d2 / ((double)M_TOT * (double)M_TOT - (double)M_TOT);
            *band = bw * 0.25;
        }
    }
}

// ---- fused MFMA tile -> d2 -> 5 gaussians -> signed partial (+ final reduce) ----
// 128x128 tile, 512 thr (8 waves 2x4, per-wave 64x32), K=256, BK=64,
// double-buffered 64 KB LDS, stage(t+1) overlapped with compute(t).
__global__ __launch_bounds__(512, 4) void k_mmd(const ushort* __restrict__ P,
        const float* __restrict__ sq, const double* __restrict__ band,
        double* __restrict__ parts, unsigned int* __restrict__ cnt,
        float* __restrict__ out) {
    // XCD-aware swizzle (2080 = 8 * 260, bijective)
    int raw = blockIdx.x;
    int t = (raw & 7) * 260 + (raw >> 3);
    // triangle decode: t -> (bi, bj), bi <= bj over 64x64 tile grid
    int bi = (int)(64.5 - sqrt(64.5 * 64.5 - 2.0 * (double)t));
    while (bi * 64 - bi * (bi - 1) / 2 > t) --bi;
    while ((bi + 1) * 64 - (bi + 1) * bi / 2 <= t) ++bi;
    int bj = bi + (t - (bi * 64 - bi * (bi - 1) / 2));

    __shared__ ushort As[2][128][64];
    __shared__ ushort Bs[2][128][64];

    int tid = threadIdx.x, lane = tid & 63, w = tid >> 6;
    int wr = w >> 2, wc = w & 3;
    int row0 = bi << 7, col0 = bj << 7;
    const ushort* Pa = P + (size_t)row0 * K_DIM;
    const ushort* Pb = P + (size_t)col0 * K_DIM;

    // hoisted fragment LDS byte-offsets; per-kk address = off ^ (kk<<6)
    int chunk0 = ((lane >> 4) ^ (lane & 7)) << 4;
    int aoff[4], boff[2];
#pragma unroll
    for (int m = 0; m < 4; ++m)
        aoff[m] = (((wr << 6) + (m << 4) + (lane & 15)) << 7) + chunk0;
#pragma unroll
    for (int n = 0; n < 2; ++n)
        boff[n] = (((wc << 5) + (n << 4) + (lane & 15)) << 7) + chunk0;

    // staging geometry: row rr (+p*64), swizzled 16B chunk, linear LDS dest
    int rr = tid >> 3;
    int sc = (tid & 7) ^ (rr & 7);
    size_t soff = (size_t)rr * K_DIM + (sc << 3);
    int ldst = tid << 4;

    f32x4 accm[4][2] = {};

    // prologue: stage buf0 (kc = 0)
#pragma unroll
    for (int p = 0; p < 2; ++p) {
        gload16(Pa + soff + (p << 14), (char*)&As[0][0][0] + (p << 13) + ldst);
        gload16(Pb + soff + (p << 14), (char*)&Bs[0][0][0] + (p << 13) + ldst);
    }
    __syncthreads();   // waits vmcnt(0): buf0 resident

#pragma unroll
    for (int it = 0; it < 4; ++it) {
        int cur = it & 1;
        if (it < 3) {          // overlap: stage next tile into the other buffer
            int kc = (it + 1) << 6;
#pragma unroll
            for (int p = 0; p < 2; ++p) {
                gload16(Pa + soff + kc + (p << 14),
                        (char*)&As[cur ^ 1][0][0] + (p << 13) + ldst);
                gload16(Pb + soff + kc + (p << 14),
                        (char*)&Bs[cur ^ 1][0][0] + (p << 13) + ldst);
            }
        }
        const char* Ab = (const char*)&As[cur][0][0];
        const char* Bb = (const char*)&Bs[cur][0][0];
#pragma unroll
        for (int kk = 0; kk < 2; ++kk) {
            short8 af[4], bf2[2];
#pragma unroll
            for (int m = 0; m < 4; ++m)
                af[m] = *(const short8*)(Ab + (aoff[m] ^ (kk << 6)));
#pragma unroll
            for (int n = 0; n < 2; ++n)
                bf2[n] = *(const short8*)(Bb + (boff[n] ^ (kk << 6)));
#pragma unroll
            for (int m = 0; m < 4; ++m)
#pragma unroll
                for (int n = 0; n < 2; ++n)
                    accm[m][n] = __builtin_amdgcn_mfma_f32_16x16x32_bf16(
                        af[m], bf2[n], accm[m][n], 0, 0, 0);
        }
        __syncthreads();   // drains staged loads; WAR-protects buffer reuse
    }

    // ---- epilogue: q = -d2*E16; t4=exp2(q); squarings give all 5 terms ----
    bool isdiag = (bi == bj);
    double bwd = *band;
    float E16 = (float)(1.4426950408889634 / (bwd * 16.0));
    float twoE16 = 2.f * E16;

    float A4[4][4];
#pragma unroll
    for (int m = 0; m < 4; ++m) {
        float4 v = *(const float4*)&sq[row0 + (wr << 6) + (m << 4) + ((lane >> 4) << 2)];
        A4[m][0] = -v.x * E16; A4[m][1] = -v.y * E16;
        A4[m][2] = -v.z * E16; A4[m][3] = -v.w * E16;
    }
    float Bv[2];
#pragma unroll
    for (int n = 0; n < 2; ++n)
        Bv[n] = -sq[col0 + (wc << 5) + (n << 4) + (lane & 15)] * E16;

    float p0 = 0.f, p1 = 0.f, p2 = 0.f, p3 = 0.f, p4 = 0.f;
#pragma unroll
    for (int m = 0; m < 4; ++m)
#pragma unroll
    for (int n = 0; n < 2; ++n) {
        int rlb = (wr << 6) + (m << 4) + ((lane >> 4) << 2);
        int cl  = (wc << 5) + (n << 4) + (lane & 15);
#pragma unroll
        for (int j = 0; j < 4; ++j) {
            float q = fmaf(accm[m][n][j], twoE16, A4[m][j] + Bv[n]);
            if (isdiag && (rlb + j == cl)) q = 0.f;   // exact-zero diagonal
            float t4 = exp2f(q);
            float t3 = t4 * t4, t2 = t3 * t3, t1 = t2 * t2, t0 = t1 * t1;
            p4 += t4; p3 += t3; p2 += t2; p1 += t1; p0 += t0;
        }
    }
    float part = (p0 + p1) + (p2 + p3) + p4;
#pragma unroll
    for (int off = 32; off > 0; off >>= 1) part += __shfl_down(part, off, 64);

    // LDS dead after main loop: reuse As for wpart/flag, Bs for f64 reduce
    float* wpart = (float*)&As[0][0][0];
    int*   lastf = (int*)(wpart + 16);
    double* dredm = (double*)&Bs[0][0][0];

    if (lane == 0) wpart[w] = part;
    __syncthreads();
    if (tid == 0) {
        float sgn = ((row0 < N_HALF) == (col0 < N_HALF)) ? 1.f : -1.f;
        float wt  = isdiag ? 1.f : 2.f;
        double tot = 0.0;
#pragma unroll
        for (int i = 0; i < 8; ++i) tot += (double)wpart[i];
        parts[raw] = tot * (double)(sgn * wt);
        __threadfence();
        unsigned int o = atomicAdd(cnt, 1u);
        *lastf = (o == NTILE - 1u);
    }
    __syncthreads();
    if (*lastf) {                      // last block: reduce all partials
        __threadfence();
        double s = 0.0;
        for (int i = tid; i < NTILE; i += 512) s += parts[i];
        dredm[tid] = s;
        __syncthreads();
        for (int off = 256; off > 0; off >>= 1) {
            if (tid < off) dredm[tid] += dredm[tid + off];
            __syncthreads();
        }
        if (tid == 0)
            out[0] = (float)(dredm[0] * (1.0 / ((double)N_HALF * (double)N_HALF)));
    }
}

extern "C" void kernel_launch(void* const* d_in, const int* in_sizes, int n_in,
                              void* d_out, int out_size, void* d_ws, size_t ws_size,
                              hipStream_t stream) {
    const float* src = (const float*)d_in[0];
    const float* tgt = (const float*)d_in[1];
    float*  sq      = (float*)((char*)d_ws + WS_SQ);
    float*  colpart = (float*)((char*)d_ws + WS_COLPART);
    double* sqd     = (double*)((char*)d_ws + WS_SQD);
    double* band    = (double*)((char*)d_ws + WS_BAND);
    unsigned int* cnt  = (unsigned int*)((char*)d_ws + WS_CNT);
    unsigned int* pcnt = (unsigned int*)((char*)d_ws + WS_PCNT);
    double* parts   = (double*)((char*)d_ws + WS_PARTS);
    ushort* P       = (ushort*)((char*)d_ws + WS_P);

    hipMemsetAsync((char*)d_ws + WS_BAND, 0, 64, stream);
    k_pack <<<256,   256, 0, stream>>>(src, tgt, P, sq, colpart, sqd, band, pcnt);
    k_mmd  <<<NTILE, 512, 0, stream>>>(P, sq, band, parts, cnt, (float*)d_out);
}